// Round 7
// baseline (180.375 us; speedup 1.0000x reference)
//
#include <hip/hip_runtime.h>
#include <hip/hip_bf16.h>
#include <hip/hip_fp16.h>

typedef _Float16 half8 __attribute__((ext_vector_type(8)));
typedef _Float16 half4 __attribute__((ext_vector_type(4)));
typedef float f32x4 __attribute__((ext_vector_type(4)));

#define LN_EPS 1e-5f
#define MASK_FILL -1e9f

// async global->LDS, 16B per lane. LDS dest is wave-uniform base + lane*16.
__device__ __forceinline__ void async16(void* lds, const void* g) {
  __builtin_amdgcn_global_load_lds(
      (__attribute__((address_space(1))) void*)(g),
      (__attribute__((address_space(3))) void*)(lds), 16, 0, 0);
}

// ---------------- cast f32 -> f16 (vec4) ----------------
__global__ __launch_bounds__(256) void cast_f32_f16_kernel(
    const float* __restrict__ in, _Float16* __restrict__ out, int n4) {
  int i = blockIdx.x * 256 + threadIdx.x;
  if (i < n4) {
    float4 v = ((const float4*)in)[i];
    half4 h = { (_Float16)v.x, (_Float16)v.y, (_Float16)v.z, (_Float16)v.w };
    ((half4*)out)[i] = h;
  }
}

// ---------------- transpose f32 [R][C] -> f16 [C][R] ----------------
__global__ __launch_bounds__(256) void transpose_f32_to_f16_kernel(
    const float* __restrict__ in, _Float16* __restrict__ out, int R, int C) {
  __shared__ float tile[32][33];
  int bc = blockIdx.x * 32, br = blockIdx.y * 32;
  int lc = threadIdx.x & 31;
  int lr0 = threadIdx.x >> 5;  // 0..7
  for (int i = lr0; i < 32; i += 8)
    tile[i][lc] = in[(size_t)(br + i) * C + bc + lc];
  __syncthreads();
  for (int i = lr0; i < 32; i += 8)
    out[(size_t)(bc + i) * R + br + lc] = (_Float16)tile[lc][i];
}

// ---------------- prep: compact rows with dmask!=0 ----------------
__global__ __launch_bounds__(256) void prep_kernel(
    const int* __restrict__ dmask, int* __restrict__ rowmap,
    float* __restrict__ row_w, int* __restrict__ start, int* __restrict__ keepM) {
  __shared__ int lsum[256];
  __shared__ int nvs[64];
  const int tid = threadIdx.x;
  int flags[8];
  int cnt = 0;
#pragma unroll
  for (int u = 0; u < 8; u++) {
    flags[u] = dmask[tid * 8 + u] != 0;
    cnt += flags[u];
  }
  if (tid < 64) {
    int c = 0;
    for (int u = 0; u < 32; u++) c += (dmask[tid * 32 + u] != 0);
    nvs[tid] = c;
  }
  lsum[tid] = cnt;
  __syncthreads();
  for (int ofs = 1; ofs < 256; ofs <<= 1) {
    int t = (tid >= ofs) ? lsum[tid - ofs] : 0;
    __syncthreads();
    lsum[tid] += t;
    __syncthreads();
  }
  int excl = lsum[tid] - cnt;
  int pos = excl;
#pragma unroll
  for (int u = 0; u < 8; u++) {
    if (flags[u]) {
      int row = tid * 8 + u;
      rowmap[pos] = row;
      row_w[pos] = 1.0f / (float)nvs[row >> 5];
      pos++;
    }
  }
  if ((tid & 3) == 0) start[tid >> 2] = excl;
  if (tid == 255) {
    start[64] = lsum[255];
    *keepM = lsum[255];
  }
}

// ---------------- gather+cast kept rows of enc (f32 [2048][768]) -> f16 ----
__global__ __launch_bounds__(256) void gather_cast_kernel(
    const float* __restrict__ src, const int* __restrict__ rowmap,
    const int* __restrict__ keepM, _Float16* __restrict__ dst) {
  const int r = blockIdx.x;
  const int t = threadIdx.x;
  const int k = *keepM;
  _Float16* d = dst + (size_t)r * 768;
  if (r < k) {
    const float* s = src + (size_t)rowmap[r] * 768;
    for (int i = t; i < 768; i += 256) d[i] = (_Float16)s[i];
  } else {
    int* di = (int*)d;
    for (int i = t; i < 384; i += 256) di[i] = 0;
  }
}

// ---------------- fp16 MFMA GEMM, double-buffered 2-phase, BK=32 ----------
// C[M][N] = alpha * A[M][K] @ Bt[N][K]^T. 128x128 tile, 4 waves (2x2),
// each wave 64x64 via 4x4 16x16x32 frags. One __syncthreads per K-step:
// stage(t+1 -> buf^1) issued BEFORE compute(buf), barrier drains both.
// LDS rows are 64B (4x16B granules); granule swizzle g ^= (row>>1)&3 via
// pre-swizzled per-lane GLOBAL src (LDS dest linear, as gload_lds needs);
// reads XOR the same -> 2 lanes/bank-slot = conflict-free.
// XCD=true: bijective chunked blockIdx swizzle (total blocks % 8 == 0).
template<bool OUT_F32, bool XCD>
__global__ __launch_bounds__(256) void gemm_f16_kernel(
    const _Float16* __restrict__ A, const _Float16* __restrict__ Bt,
    void* __restrict__ C, int M, int N, int K, float alpha,
    size_t strideBt, size_t strideC, const int* __restrict__ keepRows) {
  int bx = blockIdx.x, by = blockIdx.y, bz = blockIdx.z;
  if (XCD) {
    const int gx = gridDim.x, gy = gridDim.y;
    const int total = gx * gy * gridDim.z;
    const int L = bx + gx * (by + gy * bz);
    const int orig = (L & 7) * (total >> 3) + (L >> 3);
    bx = orig % gx;
    const int rest = orig / gx;
    by = rest % gy;
    bz = rest / gy;
  }
  const int bm = bx * 128, bn = by * 128;
  if (keepRows && bm >= *keepRows) return;
  __shared__ _Float16 As[2][128 * 32];
  __shared__ _Float16 Bs[2][128 * 32];
  const int tid = threadIdx.x;
  const size_t z = bz;
  const int wave = tid >> 6, lane = tid & 63;
  const int wr = (wave >> 1) * 64, wc = (wave & 1) * 64;
  const int fr = lane & 15;
  f32x4 acc[4][4] = {};
  // staging: one issue = 1KB = 16 rows x 64B. Wave w rows [w*32, w*32+32):
  // lane l -> row l>>2, LDS granule l&3; global granule (l&3) ^ ((l>>3)&3).
  const int srow = wave * 32 + (lane >> 2);
  const int scol = ((lane & 3) ^ ((lane >> 3) & 3)) * 8;  // elems
  const _Float16* ga = A + (size_t)(bm + srow) * K + scol;
  const _Float16* gb = Bt + z * strideBt + (size_t)(bn + srow) * K + scol;
  const int nt = K >> 5;
  auto stage = [&](int buf, int k0) {
    _Float16* la = &As[buf][(wave * 32) * 32];
    _Float16* lb = &Bs[buf][(wave * 32) * 32];
    async16(la, ga + k0);
    async16(la + 16 * 32, ga + (size_t)16 * K + k0);
    async16(lb, gb + k0);
    async16(lb + 16 * 32, gb + (size_t)16 * K + k0);
  };
  // read-side swizzled granule offset (elems): (sb ^ ((fr>>1)&3)) * 8
  const int sg = (((lane >> 4) ^ ((fr >> 1) & 3))) * 8;
  stage(0, 0);
  __syncthreads();  // prefetch(0) landed
  int cur = 0;
  for (int t = 0; t < nt; ++t) {
    if (t + 1 < nt) stage(cur ^ 1, (t + 1) * 32);
    half8 af[4], bf[4];
#pragma unroll
    for (int i = 0; i < 4; i++)
      af[i] = *(const half8*)&As[cur][(wr + i * 16 + fr) * 32 + sg];
#pragma unroll
    for (int j = 0; j < 4; j++)
      bf[j] = *(const half8*)&Bs[cur][(wc + j * 16 + fr) * 32 + sg];
#pragma unroll
    for (int i = 0; i < 4; i++)
#pragma unroll
      for (int j = 0; j < 4; j++)
        acc[i][j] = __builtin_amdgcn_mfma_f32_16x16x32_f16(af[i], bf[j], acc[i][j], 0, 0, 0);
    __syncthreads();  // drains vmcnt(0) (prefetch landed) + all LDS reads done
    cur ^= 1;
  }
  const int rg = (lane >> 4) * 4;
#pragma unroll
  for (int i = 0; i < 4; i++) {
#pragma unroll
    for (int j = 0; j < 4; j++) {
      int col = bn + wc + j * 16 + fr;
#pragma unroll
      for (int r = 0; r < 4; r++) {
        int row = bm + wr + i * 16 + rg + r;
        float v = acc[i][j][r] * alpha;
        if (OUT_F32)
          ((float*)C)[z * strideC + (size_t)row * N + col] = v;
        else
          ((_Float16*)C)[z * strideC + (size_t)row * N + col] = (_Float16)v;
      }
    }
  }
}

// ---------------- block reduce helper (256 threads, 4 waves) ----------------
__device__ __forceinline__ float block_reduce(float v, bool do_max, float* wbuf, int tid) {
#pragma unroll
  for (int m = 32; m; m >>= 1) {
    float o = __shfl_xor(v, m);
    v = do_max ? fmaxf(v, o) : (v + o);
  }
  if ((tid & 63) == 0) wbuf[tid >> 6] = v;
  __syncthreads();
  float r = do_max ? fmaxf(fmaxf(wbuf[0], wbuf[1]), fmaxf(wbuf[2], wbuf[3]))
                   : (wbuf[0] + wbuf[1] + wbuf[2] + wbuf[3]);
  __syncthreads();
  return r;
}

// ---------------- fused masked-softmax + ds-weighted combine ---------------
// One block per (kd, b). Single pass over the kept rows of this kd:
// per row: load a[16], block-max, exp in regs, block-sum, acc += (w/denom)*e.
// ca[b][kd][n] written once. i0==i1 (nv==0 corner): uniform 1/4096.
__global__ __launch_bounds__(256) void fused_softmax_kernel(
    const _Float16* __restrict__ S, const float* __restrict__ row_w,
    const int* __restrict__ start, const int* __restrict__ amask,
    float* __restrict__ ca) {
  __shared__ float wbuf[4];
  const int kd = blockIdx.x;
  const int b = blockIdx.z;
  const int tid = threadIdx.x;
  const int i0 = start[kd], i1 = start[kd + 1];
  float ca_r[16];
  if (i0 == i1) {
#pragma unroll
    for (int c = 0; c < 16; c++) ca_r[c] = 1.0f / 4096.0f;
  } else {
#pragma unroll
    for (int c = 0; c < 16; c++) ca_r[c] = 0.f;
    const int* am = amask + (size_t)b * 4096;
    bool nm[16];
#pragma unroll
    for (int h = 0; h < 2; h++) {
      int4 m0 = *(const int4*)(am + h * 2048 + tid * 8);
      int4 m1 = *(const int4*)(am + h * 2048 + tid * 8 + 4);
      nm[h * 8 + 0] = m0.x != 0; nm[h * 8 + 1] = m0.y != 0;
      nm[h * 8 + 2] = m0.z != 0; nm[h * 8 + 3] = m0.w != 0;
      nm[h * 8 + 4] = m1.x != 0; nm[h * 8 + 5] = m1.y != 0;
      nm[h * 8 + 6] = m1.z != 0; nm[h * 8 + 7] = m1.w != 0;
    }
    for (int i = i0; i < i1; i++) {
      const _Float16* sp = S + ((size_t)b * 2048 + i) * 4096;
      float a[16];
#pragma unroll
      for (int h = 0; h < 2; h++) {
        half8 v = *(const half8*)(sp + h * 2048 + tid * 8);
#pragma unroll
        for (int u = 0; u < 8; u++)
          a[h * 8 + u] = nm[h * 8 + u] ? (float)v[u] : MASK_FILL;
      }
      float mx = a[0];
#pragma unroll
      for (int c = 1; c < 16; c++) mx = fmaxf(mx, a[c]);
      mx = block_reduce(mx, true, wbuf, tid);
      float e[16];
      float ls = 0.f;
#pragma unroll
      for (int c = 0; c < 16; c++) {
        e[c] = expf(a[c] - mx);
        ls += e[c];
      }
      float denom = block_reduce(ls, false, wbuf, tid);
      float iw = row_w[i] / denom;
#pragma unroll
      for (int c = 0; c < 16; c++) ca_r[c] += iw * e[c];
    }
  }
  float* cp = ca + ((size_t)b * 64 + kd) * 4096;
#pragma unroll
  for (int h = 0; h < 2; h++)
#pragma unroll
    for (int u = 0; u < 8; u += 4) {
      float4 w4 = {ca_r[h * 8 + u], ca_r[h * 8 + u + 1],
                   ca_r[h * 8 + u + 2], ca_r[h * 8 + u + 3]};
      *(float4*)&cp[h * 2048 + tid * 8 + u] = w4;
    }
}

// ---------------- t partial: t[b*64+m][j] = sum_n ca[b][m][n] * xh[b][n][j] --
__global__ __launch_bounds__(256) void t_partial_kernel(
    const float* __restrict__ ca,     // [4][64][4096]
    const _Float16* __restrict__ xh,  // [4][4096][768] f16
    float* __restrict__ t_part) {     // [16][256][768]
  __shared__ float cas[64][68];
  __shared__ float xs[64][132];
  const int jt = blockIdx.x;  // 0..5
  const int nc = blockIdx.y;  // 0..15
  const int b = blockIdx.z;   // 0..3
  const int tid = threadIdx.x;
  const int tm = tid >> 4, tj = tid & 15;
  const int r = tid >> 2;
  const int cg = (tid & 3) * 16;  // cas cols
  const int cc = (tid & 3) * 32;  // xs cols
  float acc[4][8] = {};
  for (int n0 = nc * 256; n0 < nc * 256 + 256; n0 += 64) {
    __syncthreads();
    const float* cap = ca + (size_t)(b * 64 + r) * 4096 + n0 + cg;
#pragma unroll
    for (int u = 0; u < 16; u += 4)
      *(float4*)&cas[r][cg + u] = *(const float4*)(cap + u);
    const _Float16* xp = xh + ((size_t)b * 4096 + n0 + r) * 768 + jt * 128 + cc;
#pragma unroll
    for (int u = 0; u < 32; u += 8) {
      half8 hv = *(const half8*)(xp + u);
#pragma unroll
      for (int q = 0; q < 8; q++) xs[r][cc + u + q] = (float)hv[q];
    }
    __syncthreads();
#pragma unroll 8
    for (int nn = 0; nn < 64; ++nn) {
      float cm[4], xj[8];
#pragma unroll
      for (int i = 0; i < 4; i++) cm[i] = cas[tm * 4 + i][nn];
#pragma unroll
      for (int j = 0; j < 8; j++) xj[j] = xs[nn][tj * 8 + j];
#pragma unroll
      for (int i = 0; i < 4; i++)
#pragma unroll
        for (int j = 0; j < 8; j++) acc[i][j] += cm[i] * xj[j];
    }
  }
#pragma unroll
  for (int i = 0; i < 4; i++)
#pragma unroll
    for (int j = 0; j < 8; j++)
      t_part[((size_t)nc * 256 + b * 64 + tm * 4 + i) * 768 + jt * 128 + tj * 8 + j] = acc[i][j];
}

// reduce partials and cast to f16 for the pooled GEMM
__global__ __launch_bounds__(256) void t_reduce_kernel(
    const float* __restrict__ t_part, _Float16* __restrict__ th) {
  int i = blockIdx.x * 256 + threadIdx.x;  // < 196608
  float s = 0.f;
#pragma unroll
  for (int nc = 0; nc < 16; ++nc) s += t_part[(size_t)nc * 196608 + i];
  th[i] = (_Float16)s;
}

// ---------------- LayerNorm + final projection ----------------
__global__ __launch_bounds__(256) void ln_out_kernel(
    const float* __restrict__ pooled, const float* __restrict__ Wo,
    const float* __restrict__ bo, const float* __restrict__ gamma,
    const float* __restrict__ beta, float* __restrict__ out) {
  __shared__ float wbuf[4];
  const int row = blockIdx.x, tid = threadIdx.x;
  float p[3];
#pragma unroll
  for (int u = 0; u < 3; u++) p[u] = pooled[(size_t)row * 768 + tid + u * 256];
  float s1 = p[0] + p[1] + p[2];
  float s2 = p[0] * p[0] + p[1] * p[1] + p[2] * p[2];
  s1 = block_reduce(s1, false, wbuf, tid);
  s2 = block_reduce(s2, false, wbuf, tid);
  float mean = s1 * (1.f / 768.f);
  float var = s2 * (1.f / 768.f) - mean * mean;
  float rstd = rsqrtf(var + LN_EPS);
  float accv = 0.f;
#pragma unroll
  for (int u = 0; u < 3; u++) {
    int i = tid + u * 256;
    float y = (p[u] - mean) * rstd * gamma[i] + beta[i];
    accv += y * Wo[i];
  }
  accv = block_reduce(accv, false, wbuf, tid);
  if (tid == 0) out[row] = accv + bo[0];
}

extern "C" void kernel_launch(void* const* d_in, const int* in_sizes, int n_in,
                              void* d_out, int out_size, void* d_ws, size_t ws_size,
                              hipStream_t stream) {
  const float* x = (const float*)d_in[0];
  const float* enc = (const float*)d_in[1];
  const int* dmask = (const int*)d_in[2];
  const int* amask = (const int*)d_in[3];
  const float* Wk = (const float*)d_in[4];
  const float* Wv = (const float*)d_in[5];
  const float* Wo = (const float*)d_in[6];
  const float* bo = (const float*)d_in[7];
  const float* gamma = (const float*)d_in[8];
  const float* beta = (const float*)d_in[9];
  float* out = (float*)d_out;

  char* ws = (char*)d_ws;
  size_t off = 0;
  auto alloc = [&](size_t bytes) -> char* {
    char* p = ws + off;
    off += (bytes + 255) & ~((size_t)255);
    return p;
  };
  _Float16* xh = (_Float16*)alloc((size_t)16384 * 768 * 2);
  _Float16* wkT = (_Float16*)alloc((size_t)768 * 768 * 2);
  _Float16* wvh = (_Float16*)alloc((size_t)768 * 768 * 2);
  _Float16* enc_c = (_Float16*)alloc((size_t)2048 * 768 * 2);
  _Float16* encK_c = (_Float16*)alloc((size_t)2048 * 768 * 2);
  float* ca = (float*)alloc((size_t)4 * 64 * 4096 * 4);
  float* t_part = (float*)alloc((size_t)16 * 256 * 768 * 4);
  _Float16* th = (_Float16*)alloc((size_t)256 * 768 * 2);
  float* pooled = (float*)alloc((size_t)256 * 768 * 4);
  int* rowmap = (int*)alloc(2048 * 4);
  float* row_w = (float*)alloc(2048 * 4);
  int* start = (int*)alloc(65 * 4);
  int* keepM = (int*)alloc(4);

  // batched path needs 4 S buffers (67.1 MB); fallback needs 1 (16.8 MB)
  const size_t s_one = (size_t)2048 * 4096 * 2;
  const bool batched = (off + 4 * s_one) <= ws_size;
  _Float16* S = (_Float16*)alloc(batched ? 4 * s_one : s_one);

  const float scale = 0.036084391824351615f;  // 1/sqrt(768)

  prep_kernel<<<1, 256, 0, stream>>>(dmask, rowmap, row_w, start, keepM);
  cast_f32_f16_kernel<<<12288, 256, 0, stream>>>(x, xh, 16384 * 768 / 4);
  cast_f32_f16_kernel<<<576, 256, 0, stream>>>(Wv, wvh, 768 * 768 / 4);
  transpose_f32_to_f16_kernel<<<dim3(24, 24), 256, 0, stream>>>(Wk, wkT, 768, 768);
  gather_cast_kernel<<<2048, 256, 0, stream>>>(enc, rowmap, keepM, enc_c);

  // encK_c = enc_c @ Wk   [keepM x 768]
  gemm_f16_kernel<false, false><<<dim3(16, 6), 256, 0, stream>>>(
      enc_c, wkT, encK_c, 2048, 768, 768, 1.0f, 0, 0, keepM);

  if (batched) {
    gemm_f16_kernel<false, true><<<dim3(16, 32, 4), 256, 0, stream>>>(
        encK_c, xh, S, 2048, 4096, 768, scale,
        (size_t)4096 * 768, (size_t)2048 * 4096, keepM);
    fused_softmax_kernel<<<dim3(64, 1, 4), 256, 0, stream>>>(
        S, row_w, start, amask, ca);
  } else {
    for (int b = 0; b < 4; b++) {
      gemm_f16_kernel<false, true><<<dim3(16, 32), 256, 0, stream>>>(
          encK_c, xh + (size_t)b * 4096 * 768, S, 2048, 4096, 768, scale, 0, 0, keepM);
      fused_softmax_kernel<<<dim3(64, 1, 1), 256, 0, stream>>>(
          S, row_w, start, amask + (size_t)b * 4096, ca + (size_t)b * 64 * 4096);
    }
  }

  // t = ca @ xh  (fp32 accum), split over n-chunks then reduced to f16
  t_partial_kernel<<<dim3(6, 16, 4), 256, 0, stream>>>(ca, xh, t_part);
  t_reduce_kernel<<<768, 256, 0, stream>>>(t_part, th);
  // pooled = t @ Wv^T  [256 x 768] fp32
  gemm_f16_kernel<true, false><<<dim3(2, 6), 256, 0, stream>>>(
      th, wvh, pooled, 256, 768, 768, 1.0f, 0, 0, nullptr);
  ln_out_kernel<<<256, 256, 0, stream>>>(pooled, Wo, bo, gamma, beta, out);
}

// Round 8
// 153.888 us; speedup vs baseline: 1.1721x; 1.1721x over previous
//
#include <hip/hip_runtime.h>
#include <hip/hip_bf16.h>
#include <hip/hip_fp16.h>

typedef _Float16 half8 __attribute__((ext_vector_type(8)));
typedef _Float16 half4 __attribute__((ext_vector_type(4)));
typedef _Float16 half2v __attribute__((ext_vector_type(2)));
typedef float f32x4 __attribute__((ext_vector_type(4)));

#define LN_EPS 1e-5f
#define MASK_FILL -1e9f

// async global->LDS, 16B per lane. LDS dest is wave-uniform base + lane*16.
__device__ __forceinline__ void async16(void* lds, const void* g) {
  __builtin_amdgcn_global_load_lds(
      (__attribute__((address_space(1))) void*)(g),
      (__attribute__((address_space(3))) void*)(lds), 16, 0, 0);
}

// ---------------- prep_all ----------------
// block 0: compact dmask rows -> rowmap, row_w, start[65], keepM
// blocks 1..4: per-batch column PERMUTATION of amask: valid n first (cntN),
//              then invalid, in stable order -> perm[b][4096], cntN[b].
__global__ __launch_bounds__(256) void prep_all_kernel(
    const int* __restrict__ dmask, const int* __restrict__ amask,
    int* __restrict__ rowmap, float* __restrict__ row_w,
    int* __restrict__ start, int* __restrict__ keepM,
    int* __restrict__ perm, int* __restrict__ cntN) {
  __shared__ int lsum[256];
  __shared__ int nvs[64];
  const int tid = threadIdx.x;
  if (blockIdx.x == 0) {
    int flags[8];
    int cnt = 0;
#pragma unroll
    for (int u = 0; u < 8; u++) {
      flags[u] = dmask[tid * 8 + u] != 0;
      cnt += flags[u];
    }
    if (tid < 64) {
      int c = 0;
      for (int u = 0; u < 32; u++) c += (dmask[tid * 32 + u] != 0);
      nvs[tid] = c;
    }
    lsum[tid] = cnt;
    __syncthreads();
    for (int ofs = 1; ofs < 256; ofs <<= 1) {
      int t = (tid >= ofs) ? lsum[tid - ofs] : 0;
      __syncthreads();
      lsum[tid] += t;
      __syncthreads();
    }
    int excl = lsum[tid] - cnt;
    int pos = excl;
#pragma unroll
    for (int u = 0; u < 8; u++) {
      if (flags[u]) {
        int row = tid * 8 + u;
        rowmap[pos] = row;
        row_w[pos] = 1.0f / (float)nvs[row >> 5];
        pos++;
      }
    }
    if ((tid & 3) == 0) start[tid >> 2] = excl;
    if (tid == 255) {
      start[64] = lsum[255];
      *keepM = lsum[255];
    }
  } else {
    const int b = blockIdx.x - 1;
    const int* am = amask + (size_t)b * 4096;
    int flags[16];
    int cnt = 0;
#pragma unroll
    for (int u = 0; u < 16; u++) {
      flags[u] = am[tid * 16 + u] != 0;
      cnt += flags[u];
    }
    lsum[tid] = cnt;
    __syncthreads();
    for (int ofs = 1; ofs < 256; ofs <<= 1) {
      int t = (tid >= ofs) ? lsum[tid - ofs] : 0;
      __syncthreads();
      lsum[tid] += t;
      __syncthreads();
    }
    const int total = lsum[255];
    int vpos = lsum[tid] - cnt;              // valid exclusive scan
    int ipos = total + (tid * 16 - vpos);    // invalid exclusive scan
    int* pm = perm + (size_t)b * 4096;
#pragma unroll
    for (int u = 0; u < 16; u++) {
      int g = tid * 16 + u;
      if (flags[u]) pm[vpos++] = g;
      else pm[ipos++] = g;
    }
    if (tid == 0) cntN[b] = total;
  }
}

// ---------------- gather_cast_all ----------------
// [0,16384): xh_c[b][i] = (f16) x[b][perm[b][i]]          (b = bid>>12)
// [16384,18432): enc_c[r] = (f16) enc[rowmap[r]] (pad 0)
// [18432,19008): wvh cast (1024 f32 per block)
// [19008,19584): wkT transpose 32x32 tile (24x24 grid)
__global__ __launch_bounds__(256) void gather_cast_all_kernel(
    const float* __restrict__ x, const float* __restrict__ enc,
    const float* __restrict__ Wv, const float* __restrict__ Wk,
    const int* __restrict__ perm, const int* __restrict__ rowmap,
    const int* __restrict__ keepM,
    _Float16* __restrict__ xh_c, _Float16* __restrict__ enc_c,
    _Float16* __restrict__ wvh, _Float16* __restrict__ wkT) {
  __shared__ float tile[32][33];
  const int bid = blockIdx.x;
  const int t = threadIdx.x;
  if (bid < 16384) {
    const int b = bid >> 12, ci = bid & 4095;
    const int n = perm[(size_t)b * 4096 + ci];
    const float* s = x + ((size_t)b * 4096 + n) * 768;
    _Float16* d = xh_c + ((size_t)b * 4096 + ci) * 768;
#pragma unroll
    for (int u = 0; u < 3; u++) d[t + u * 256] = (_Float16)s[t + u * 256];
  } else if (bid < 18432) {
    const int r = bid - 16384;
    _Float16* d = enc_c + (size_t)r * 768;
    if (r < *keepM) {
      const float* s = enc + (size_t)rowmap[r] * 768;
#pragma unroll
      for (int u = 0; u < 3; u++) d[t + u * 256] = (_Float16)s[t + u * 256];
    } else {
      int* di = (int*)d;
      for (int i = t; i < 384; i += 256) di[i] = 0;
    }
  } else if (bid < 19008) {
    const int base = (bid - 18432) * 1024 + t * 4;
    float4 v = *(const float4*)(Wv + base);
    half4 h = { (_Float16)v.x, (_Float16)v.y, (_Float16)v.z, (_Float16)v.w };
    *(half4*)(wkT ? (wvh + base) : (wvh + base)) = h;  // wvh cast
  } else {
    const int tb = bid - 19008;
    const int bc = (tb % 24) * 32, br = (tb / 24) * 32;
    const int lc = t & 31, lr0 = t >> 5;
    for (int i = lr0; i < 32; i += 8)
      tile[i][lc] = Wk[(size_t)(br + i) * 768 + bc + lc];
    __syncthreads();
    for (int i = lr0; i < 32; i += 8)
      wkT[(size_t)(bc + i) * 768 + br + lc] = (_Float16)tile[lc][i];
  }
}

// ---------------- fp16 MFMA GEMM, R6-proven: BK=64, XOR-swizzled LDS -------
// C[M][N] = alpha * A[M][K] @ Bt[N][K]^T. 128x128 tile, 4 waves (2x2),
// 4x4 16x16x32 frags x2 k-subtiles. LDS[row][slot]=orig[row][slot^(row&7)]
// via pre-swizzled per-lane GLOBAL src; reads XOR the same -> conflict-free.
// keepRows: early-exit bm >= *keepRows. keepN: early-exit bn >= keepN[z].
// XCD: bijective chunked blockIdx swizzle (total blocks % 8 == 0).
template<bool OUT_F32, bool XCD>
__global__ __launch_bounds__(256) void gemm_f16_kernel(
    const _Float16* __restrict__ A, const _Float16* __restrict__ Bt,
    void* __restrict__ C, int M, int N, int K, float alpha,
    size_t strideBt, size_t strideC, const int* __restrict__ keepRows,
    const int* __restrict__ keepN) {
  int bx = blockIdx.x, by = blockIdx.y, bz = blockIdx.z;
  if (XCD) {
    const int gx = gridDim.x, gy = gridDim.y;
    const int total = gx * gy * gridDim.z;
    const int L = bx + gx * (by + gy * bz);
    const int orig = (L & 7) * (total >> 3) + (L >> 3);
    bx = orig % gx;
    const int rest = orig / gx;
    by = rest % gy;
    bz = rest / gy;
  }
  const int bm = bx * 128, bn = by * 128;
  if (keepRows && bm >= *keepRows) return;
  if (keepN && bn >= keepN[bz]) return;
  __shared__ _Float16 As[128 * 64];
  __shared__ _Float16 Bs[128 * 64];
  const int tid = threadIdx.x;
  const size_t z = bz;
  const int wave = tid >> 6, lane = tid & 63;
  const int wr = (wave >> 1) * 64, wc = (wave & 1) * 64;
  const int fr = lane & 15, xr = lane & 7;
  f32x4 acc[4][4] = {};
  const int srow = wave * 32 + (lane >> 3);
  const int scol = (((lane & 7) ^ (lane >> 3))) * 8;  // elems
  const _Float16* ga = A + (size_t)(bm + srow) * K + scol;
  const _Float16* gb = Bt + z * strideBt + (size_t)(bn + srow) * K + scol;
  _Float16* lA = &As[(wave * 32) * 64];
  _Float16* lB = &Bs[(wave * 32) * 64];
  for (int k0 = 0; k0 < K; k0 += 64) {
    __syncthreads();
#pragma unroll
    for (int i = 0; i < 4; i++) {
      async16(lA + i * 8 * 64, ga + (size_t)(8 * i) * K + k0);
      async16(lB + i * 8 * 64, gb + (size_t)(8 * i) * K + k0);
    }
    __syncthreads();
#pragma unroll
    for (int k2 = 0; k2 < 2; k2++) {
      const int sb = k2 * 4 + (lane >> 4);
      const int so = (sb ^ xr) * 8;
      half8 af[4], bf[4];
#pragma unroll
      for (int i = 0; i < 4; i++)
        af[i] = *(const half8*)&As[(wr + i * 16 + fr) * 64 + so];
#pragma unroll
      for (int j = 0; j < 4; j++)
        bf[j] = *(const half8*)&Bs[(wc + j * 16 + fr) * 64 + so];
#pragma unroll
      for (int i = 0; i < 4; i++)
#pragma unroll
        for (int j = 0; j < 4; j++)
          acc[i][j] = __builtin_amdgcn_mfma_f32_16x16x32_f16(af[i], bf[j], acc[i][j], 0, 0, 0);
    }
  }
  const int rg = (lane >> 4) * 4;
#pragma unroll
  for (int i = 0; i < 4; i++) {
#pragma unroll
    for (int j = 0; j < 4; j++) {
      int col = bn + wc + j * 16 + fr;
#pragma unroll
      for (int r = 0; r < 4; r++) {
        int row = bm + wr + i * 16 + rg + r;
        float v = acc[i][j][r] * alpha;
        if (OUT_F32)
          ((float*)C)[z * strideC + (size_t)row * N + col] = v;
        else
          ((_Float16*)C)[z * strideC + (size_t)row * N + col] = (_Float16)v;
      }
    }
  }
}

// ---------------- block reduce helper (256 threads, 4 waves) ----------------
__device__ __forceinline__ float block_reduce(float v, bool do_max, float* wbuf, int tid) {
#pragma unroll
  for (int m = 32; m; m >>= 1) {
    float o = __shfl_xor(v, m);
    v = do_max ? fmaxf(v, o) : (v + o);
  }
  if ((tid & 63) == 0) wbuf[tid >> 6] = v;
  __syncthreads();
  float r = do_max ? fmaxf(fmaxf(wbuf[0], wbuf[1]), fmaxf(wbuf[2], wbuf[3]))
                   : (wbuf[0] + wbuf[1] + wbuf[2] + wbuf[3]);
  __syncthreads();
  return r;
}

// ---------------- pass 1: per-compact-row softmax stats (compact cols) -----
// One block per (kept row, batch). Only cols < cntN[b] are valid (no amask
// needed). stats_c[b*2048+r] = (rowmax, w/denom, 0, 0).
__global__ __launch_bounds__(256) void row_stats_kernel(
    const _Float16* __restrict__ S, const float* __restrict__ row_w,
    const int* __restrict__ keepM, const int* __restrict__ cntN,
    float4* __restrict__ stats_c) {
  const int r = blockIdx.x;
  if (r >= *keepM) return;
  __shared__ float wbuf[4];
  const int b = blockIdx.z;
  const int tid = threadIdx.x;
  const int cnt = cntN[b];
  if (cnt == 0) return;  // batch-wide uniform corner handled in combine
  const float w = row_w[r];
  const _Float16* sp = S + ((size_t)b * 2048 + r) * 4096 + tid * 16;
  float a[16];
  {
    half8 v0 = *(const half8*)(sp);
    half8 v1 = *(const half8*)(sp + 8);
    const int c0 = tid * 16;
#pragma unroll
    for (int u = 0; u < 8; u++) {
      a[u] = (c0 + u < cnt) ? (float)v0[u] : MASK_FILL;
      a[8 + u] = (c0 + 8 + u < cnt) ? (float)v1[u] : MASK_FILL;
    }
  }
  float mx = a[0];
#pragma unroll
  for (int c = 1; c < 16; c++) mx = fmaxf(mx, a[c]);
  mx = block_reduce(mx, true, wbuf, tid);
  float ls = 0.f;
#pragma unroll
  for (int c = 0; c < 16; c++) ls += expf(a[c] - mx);
  float denom = block_reduce(ls, false, wbuf, tid);
  if (tid == 0)
    stats_c[(size_t)b * 2048 + r] = make_float4(mx, w / denom, 0.f, 0.f);
}

// ---------------- pass 2: ds-weighted combine (compact layout) -------------
// ca_c[b][kd][i] = sum_rows iw * exp(S - mx) for i < cnt; 0 for i >= cnt.
// Uniform corners (no kept rows, or cnt==0): 1/4096 everywhere (permutation-
// invariant, matches reference exactly).
__global__ __launch_bounds__(256) void combine_kernel(
    const _Float16* __restrict__ S, const float4* __restrict__ stats_c,
    const int* __restrict__ start, const int* __restrict__ cntN,
    float* __restrict__ ca) {
  const int kd = blockIdx.x;
  const int b = blockIdx.z;
  const int i = blockIdx.y * 512 + threadIdx.x * 2;
  const int i0 = start[kd], i1 = start[kd + 1];
  const int cnt = cntN[b];
  float acc0, acc1;
  if (i0 == i1 || cnt == 0) {
    acc0 = acc1 = 1.0f / 4096.0f;
  } else if (i >= cnt) {
    acc0 = acc1 = 0.f;
  } else {
    acc0 = 0.f;
    acc1 = 0.f;
    const _Float16* sp = S + ((size_t)b * 2048 + i0) * 4096 + i;
    for (int r = i0; r < i1; r++, sp += 4096) {
      float4 s4 = stats_c[(size_t)b * 2048 + r];
      half2v v = *(const half2v*)sp;
      acc0 += s4.y * expf((float)v[0] - s4.x);
      acc1 += s4.y * expf((float)v[1] - s4.x);
    }
    if (i + 1 >= cnt) acc1 = 0.f;  // odd-cnt edge
  }
  float2 rr = {acc0, acc1};
  *(float2*)&ca[((size_t)b * 64 + kd) * 4096 + i] = rr;
}

// ---------------- t partial: t[b*64+m][j] = sum_i ca_c[b][m][i]*xh_c[b][i][j]
__global__ __launch_bounds__(256) void t_partial_kernel(
    const float* __restrict__ ca,     // [4][64][4096] compact
    const _Float16* __restrict__ xh,  // [4][4096][768] f16 compact (permuted)
    float* __restrict__ t_part) {     // [16][256][768]
  __shared__ float cas[64][68];
  __shared__ float xs[64][132];
  const int jt = blockIdx.x;  // 0..5
  const int nc = blockIdx.y;  // 0..15
  const int b = blockIdx.z;   // 0..3
  const int tid = threadIdx.x;
  const int tm = tid >> 4, tj = tid & 15;
  const int r = tid >> 2;
  const int cg = (tid & 3) * 16;
  const int cc = (tid & 3) * 32;
  float acc[4][8] = {};
  for (int n0 = nc * 256; n0 < nc * 256 + 256; n0 += 64) {
    __syncthreads();
    const float* cap = ca + (size_t)(b * 64 + r) * 4096 + n0 + cg;
#pragma unroll
    for (int u = 0; u < 16; u += 4)
      *(float4*)&cas[r][cg + u] = *(const float4*)(cap + u);
    const _Float16* xp = xh + ((size_t)b * 4096 + n0 + r) * 768 + jt * 128 + cc;
#pragma unroll
    for (int u = 0; u < 32; u += 8) {
      half8 hv = *(const half8*)(xp + u);
#pragma unroll
      for (int q = 0; q < 8; q++) xs[r][cc + u + q] = (float)hv[q];
    }
    __syncthreads();
#pragma unroll 8
    for (int nn = 0; nn < 64; ++nn) {
      float cm[4], xj[8];
#pragma unroll
      for (int i = 0; i < 4; i++) cm[i] = cas[tm * 4 + i][nn];
#pragma unroll
      for (int j = 0; j < 8; j++) xj[j] = xs[nn][tj * 8 + j];
#pragma unroll
      for (int i = 0; i < 4; i++)
#pragma unroll
        for (int j = 0; j < 8; j++) acc[i][j] += cm[i] * xj[j];
    }
  }
#pragma unroll
  for (int i = 0; i < 4; i++)
#pragma unroll
    for (int j = 0; j < 8; j++)
      t_part[((size_t)nc * 256 + b * 64 + tm * 4 + i) * 768 + jt * 128 + tj * 8 + j] = acc[i][j];
}

// reduce partials and cast to f16 for the pooled GEMM
__global__ __launch_bounds__(256) void t_reduce_kernel(
    const float* __restrict__ t_part, _Float16* __restrict__ th) {
  int i = blockIdx.x * 256 + threadIdx.x;  // < 196608
  float s = 0.f;
#pragma unroll
  for (int nc = 0; nc < 16; ++nc) s += t_part[(size_t)nc * 196608 + i];
  th[i] = (_Float16)s;
}

// ---------------- LayerNorm + final projection ----------------
__global__ __launch_bounds__(256) void ln_out_kernel(
    const float* __restrict__ pooled, const float* __restrict__ Wo,
    const float* __restrict__ bo, const float* __restrict__ gamma,
    const float* __restrict__ beta, float* __restrict__ out) {
  __shared__ float wbuf[4];
  const int row = blockIdx.x, tid = threadIdx.x;
  float p[3];
#pragma unroll
  for (int u = 0; u < 3; u++) p[u] = pooled[(size_t)row * 768 + tid + u * 256];
  float s1 = p[0] + p[1] + p[2];
  float s2 = p[0] * p[0] + p[1] * p[1] + p[2] * p[2];
  s1 = block_reduce(s1, false, wbuf, tid);
  s2 = block_reduce(s2, false, wbuf, tid);
  float mean = s1 * (1.f / 768.f);
  float var = s2 * (1.f / 768.f) - mean * mean;
  float rstd = rsqrtf(var + LN_EPS);
  float accv = 0.f;
#pragma unroll
  for (int u = 0; u < 3; u++) {
    int i = tid + u * 256;
    float y = (p[u] - mean) * rstd * gamma[i] + beta[i];
    accv += y * Wo[i];
  }
  accv = block_reduce(accv, false, wbuf, tid);
  if (tid == 0) out[row] = accv + bo[0];
}

extern "C" void kernel_launch(void* const* d_in, const int* in_sizes, int n_in,
                              void* d_out, int out_size, void* d_ws, size_t ws_size,
                              hipStream_t stream) {
  const float* x = (const float*)d_in[0];
  const float* enc = (const float*)d_in[1];
  const int* dmask = (const int*)d_in[2];
  const int* amask = (const int*)d_in[3];
  const float* Wk = (const float*)d_in[4];
  const float* Wv = (const float*)d_in[5];
  const float* Wo = (const float*)d_in[6];
  const float* bo = (const float*)d_in[7];
  const float* gamma = (const float*)d_in[8];
  const float* beta = (const float*)d_in[9];
  float* out = (float*)d_out;

  char* ws = (char*)d_ws;
  size_t off = 0;
  auto alloc = [&](size_t bytes) -> char* {
    char* p = ws + off;
    off += (bytes + 255) & ~((size_t)255);
    return p;
  };
  _Float16* xh_c = (_Float16*)alloc((size_t)16384 * 768 * 2);
  _Float16* wkT = (_Float16*)alloc((size_t)768 * 768 * 2);
  _Float16* wvh = (_Float16*)alloc((size_t)768 * 768 * 2);
  _Float16* enc_c = (_Float16*)alloc((size_t)2048 * 768 * 2);
  _Float16* encK_c = (_Float16*)alloc((size_t)2048 * 768 * 2);
  float* ca = (float*)alloc((size_t)4 * 64 * 4096 * 4);
  float* t_part = (float*)alloc((size_t)16 * 256 * 768 * 4);
  _Float16* th = (_Float16*)alloc((size_t)256 * 768 * 2);
  float* pooled = (float*)alloc((size_t)256 * 768 * 4);
  float4* stats_c = (float4*)alloc((size_t)4 * 2048 * 16);
  int* rowmap = (int*)alloc(2048 * 4);
  float* row_w = (float*)alloc(2048 * 4);
  int* start = (int*)alloc(65 * 4);
  int* keepM = (int*)alloc(4);
  int* perm = (int*)alloc((size_t)4 * 4096 * 4);
  int* cntN = (int*)alloc(4 * 4);

  // batched path needs 4 S buffers (67.1 MB); fallback needs 1 (16.8 MB)
  const size_t s_one = (size_t)2048 * 4096 * 2;
  const bool batched = (off + 4 * s_one) <= ws_size;
  _Float16* S = (_Float16*)alloc(batched ? 4 * s_one : s_one);

  const float scale = 0.036084391824351615f;  // 1/sqrt(768)

  prep_all_kernel<<<5, 256, 0, stream>>>(
      dmask, amask, rowmap, row_w, start, keepM, perm, cntN);
  gather_cast_all_kernel<<<19584, 256, 0, stream>>>(
      x, enc, Wv, Wk, perm, rowmap, keepM, xh_c, enc_c, wvh, wkT);

  // encK_c = enc_c @ Wk   [keepM x 768]
  gemm_f16_kernel<false, false><<<dim3(16, 6), 256, 0, stream>>>(
      enc_c, wkT, encK_c, 2048, 768, 768, 1.0f, 0, 0, keepM, nullptr);

  if (batched) {
    gemm_f16_kernel<false, true><<<dim3(16, 32, 4), 256, 0, stream>>>(
        encK_c, xh_c, S, 2048, 4096, 768, scale,
        (size_t)4096 * 768, (size_t)2048 * 4096, keepM, cntN);
    row_stats_kernel<<<dim3(2048, 1, 4), 256, 0, stream>>>(
        S, row_w, keepM, cntN, stats_c);
    combine_kernel<<<dim3(64, 8, 4), 256, 0, stream>>>(
        S, stats_c, start, cntN, ca);
  } else {
    for (int b = 0; b < 4; b++) {
      gemm_f16_kernel<false, true><<<dim3(16, 32), 256, 0, stream>>>(
          encK_c, xh_c + (size_t)b * 4096 * 768, S, 2048, 4096, 768, scale,
          0, 0, keepM, cntN + b);
      row_stats_kernel<<<dim3(2048, 1, 1), 256, 0, stream>>>(
          S, row_w, keepM, cntN + b, stats_c + (size_t)b * 2048);
      combine_kernel<<<dim3(64, 8, 1), 256, 0, stream>>>(
          S, stats_c + (size_t)b * 2048, start, cntN + b,
          ca + (size_t)b * 64 * 4096);
    }
  }

  // t = ca_c @ xh_c  (fp32 accum), split over n-chunks then reduced to f16
  t_partial_kernel<<<dim3(6, 16, 4), 256, 0, stream>>>(ca, xh_c, t_part);
  t_reduce_kernel<<<768, 256, 0, stream>>>(t_part, th);
  // pooled = t @ Wv^T  [256 x 768] fp32
  gemm_f16_kernel<true, false><<<dim3(2, 6), 256, 0, stream>>>(
      th, wvh, pooled, 256, 768, 768, 1.0f, 0, 0, nullptr, nullptr);
  ln_out_kernel<<<256, 256, 0, stream>>>(pooled, Wo, bo, gamma, beta, out);
}

// Round 9
// 141.383 us; speedup vs baseline: 1.2758x; 1.0884x over previous
//
#include <hip/hip_runtime.h>
#include <hip/hip_bf16.h>
#include <hip/hip_fp16.h>

typedef _Float16 half8 __attribute__((ext_vector_type(8)));
typedef _Float16 half4 __attribute__((ext_vector_type(4)));
typedef _Float16 half2v __attribute__((ext_vector_type(2)));
typedef float f32x4 __attribute__((ext_vector_type(4)));

#define LN_EPS 1e-5f
#define MASK_FILL -1e9f

// async global->LDS, 16B per lane. LDS dest is wave-uniform base + lane*16.
__device__ __forceinline__ void async16(void* lds, const void* g) {
  __builtin_amdgcn_global_load_lds(
      (__attribute__((address_space(1))) void*)(g),
      (__attribute__((address_space(3))) void*)(lds), 16, 0, 0);
}

// ---------------- prep_all ----------------
// block 0: compact dmask rows -> rowmap, row_w, start[65], keepM
// blocks 1..4: per-batch column PERMUTATION of amask: valid n first (cntN),
//              then invalid, in stable order -> perm[b][4096], cntN[b].
__global__ __launch_bounds__(256) void prep_all_kernel(
    const int* __restrict__ dmask, const int* __restrict__ amask,
    int* __restrict__ rowmap, float* __restrict__ row_w,
    int* __restrict__ start, int* __restrict__ keepM,
    int* __restrict__ perm, int* __restrict__ cntN) {
  __shared__ int lsum[256];
  __shared__ int nvs[64];
  const int tid = threadIdx.x;
  if (blockIdx.x == 0) {
    int flags[8];
    int cnt = 0;
#pragma unroll
    for (int u = 0; u < 8; u++) {
      flags[u] = dmask[tid * 8 + u] != 0;
      cnt += flags[u];
    }
    if (tid < 64) {
      int c = 0;
      for (int u = 0; u < 32; u++) c += (dmask[tid * 32 + u] != 0);
      nvs[tid] = c;
    }
    lsum[tid] = cnt;
    __syncthreads();
    for (int ofs = 1; ofs < 256; ofs <<= 1) {
      int t = (tid >= ofs) ? lsum[tid - ofs] : 0;
      __syncthreads();
      lsum[tid] += t;
      __syncthreads();
    }
    int excl = lsum[tid] - cnt;
    int pos = excl;
#pragma unroll
    for (int u = 0; u < 8; u++) {
      if (flags[u]) {
        int row = tid * 8 + u;
        rowmap[pos] = row;
        row_w[pos] = 1.0f / (float)nvs[row >> 5];
        pos++;
      }
    }
    if ((tid & 3) == 0) start[tid >> 2] = excl;
    if (tid == 255) {
      start[64] = lsum[255];
      *keepM = lsum[255];
    }
  } else {
    const int b = blockIdx.x - 1;
    const int* am = amask + (size_t)b * 4096;
    int flags[16];
    int cnt = 0;
#pragma unroll
    for (int u = 0; u < 16; u++) {
      flags[u] = am[tid * 16 + u] != 0;
      cnt += flags[u];
    }
    lsum[tid] = cnt;
    __syncthreads();
    for (int ofs = 1; ofs < 256; ofs <<= 1) {
      int t = (tid >= ofs) ? lsum[tid - ofs] : 0;
      __syncthreads();
      lsum[tid] += t;
      __syncthreads();
    }
    const int total = lsum[255];
    int vpos = lsum[tid] - cnt;              // valid exclusive scan
    int ipos = total + (tid * 16 - vpos);    // invalid exclusive scan
    int* pm = perm + (size_t)b * 4096;
#pragma unroll
    for (int u = 0; u < 16; u++) {
      int g = tid * 16 + u;
      if (flags[u]) pm[vpos++] = g;
      else pm[ipos++] = g;
    }
    if (tid == 0) cntN[b] = total;
  }
}

// ---------------- gather_cast_all ----------------
// [0,16384): xh_c[b][i] = (f16) x[b][perm[b][i]]          (b = bid>>12)
// [16384,18432): enc_c[r] = (f16) enc[rowmap[r]] (pad 0)
// [18432,19008): wvh cast (1024 f32 per block)
// [19008,19584): wkT transpose 32x32 tile (24x24 grid)
__global__ __launch_bounds__(256) void gather_cast_all_kernel(
    const float* __restrict__ x, const float* __restrict__ enc,
    const float* __restrict__ Wv, const float* __restrict__ Wk,
    const int* __restrict__ perm, const int* __restrict__ rowmap,
    const int* __restrict__ keepM,
    _Float16* __restrict__ xh_c, _Float16* __restrict__ enc_c,
    _Float16* __restrict__ wvh, _Float16* __restrict__ wkT) {
  __shared__ float tile[32][33];
  const int bid = blockIdx.x;
  const int t = threadIdx.x;
  if (bid < 16384) {
    const int b = bid >> 12, ci = bid & 4095;
    const int n = perm[(size_t)b * 4096 + ci];
    const float* s = x + ((size_t)b * 4096 + n) * 768;
    _Float16* d = xh_c + ((size_t)b * 4096 + ci) * 768;
#pragma unroll
    for (int u = 0; u < 3; u++) d[t + u * 256] = (_Float16)s[t + u * 256];
  } else if (bid < 18432) {
    const int r = bid - 16384;
    _Float16* d = enc_c + (size_t)r * 768;
    if (r < *keepM) {
      const float* s = enc + (size_t)rowmap[r] * 768;
#pragma unroll
      for (int u = 0; u < 3; u++) d[t + u * 256] = (_Float16)s[t + u * 256];
    } else {
      int* di = (int*)d;
      for (int i = t; i < 384; i += 256) di[i] = 0;
    }
  } else if (bid < 19008) {
    const int base = (bid - 18432) * 1024 + t * 4;
    float4 v = *(const float4*)(Wv + base);
    half4 h = { (_Float16)v.x, (_Float16)v.y, (_Float16)v.z, (_Float16)v.w };
    *(half4*)(wvh + base) = h;
  } else {
    const int tb = bid - 19008;
    const int bc = (tb % 24) * 32, br = (tb / 24) * 32;
    const int lc = t & 31, lr0 = t >> 5;
    for (int i = lr0; i < 32; i += 8)
      tile[i][lc] = Wk[(size_t)(br + i) * 768 + bc + lc];
    __syncthreads();
    for (int i = lr0; i < 32; i += 8)
      wkT[(size_t)(bc + i) * 768 + br + lc] = (_Float16)tile[lc][i];
  }
}

// ---------------- fp16 MFMA GEMM: 64x128 tile, BK=64, XOR-swizzled LDS -----
// C[M][N] = alpha * A[M][K] @ Bt[N][K]^T. 4 waves (2Mx2N), wave tile 32x64
// (acc[2][4] 16x16x32 frags, 2 k-subtiles). Smaller tile than R6's 128x128
// to get ~4 active blocks/CU after keepRows/keepN early-exits (latency hiding
// across blocks, m114). LDS[row][slot]=orig[row][slot^(row&7)] via
// pre-swizzled per-lane GLOBAL src; reads XOR the same -> conflict-free.
// XCD: bijective chunked blockIdx swizzle (total blocks % 8 == 0).
template<bool OUT_F32, bool XCD>
__global__ __launch_bounds__(256) void gemm_f16_kernel(
    const _Float16* __restrict__ A, const _Float16* __restrict__ Bt,
    void* __restrict__ C, int M, int N, int K, float alpha,
    size_t strideBt, size_t strideC, const int* __restrict__ keepRows,
    const int* __restrict__ keepN) {
  int bx = blockIdx.x, by = blockIdx.y, bz = blockIdx.z;
  if (XCD) {
    const int gx = gridDim.x, gy = gridDim.y;
    const int total = gx * gy * gridDim.z;
    const int L = bx + gx * (by + gy * bz);
    const int orig = (L & 7) * (total >> 3) + (L >> 3);
    bx = orig % gx;
    const int rest = orig / gx;
    by = rest % gy;
    bz = rest / gy;
  }
  const int bm = bx * 64, bn = by * 128;
  if (keepRows && bm >= *keepRows) return;
  if (keepN && bn >= keepN[bz]) return;
  __shared__ _Float16 As[64 * 64];
  __shared__ _Float16 Bs[128 * 64];
  const int tid = threadIdx.x;
  const size_t z = bz;
  const int wave = tid >> 6, lane = tid & 63;
  const int wr = (wave >> 1) * 32, wc = (wave & 1) * 64;
  const int fr = lane & 15, xr = lane & 7;
  f32x4 acc[2][4] = {};
  // staging: each issue = 8 rows x 128B; lane l -> row l>>3, granule
  // (l&7)^(l>>3) (row&7 == l>>3: wave bases and issue strides are mult of 8).
  const int lrow = lane >> 3;
  const int scol = (((lane & 7) ^ lrow)) * 8;  // elems
  const _Float16* ga = A + (size_t)(bm + wave * 16 + lrow) * K + scol;
  const _Float16* gb = Bt + z * strideBt + (size_t)(bn + wave * 32 + lrow) * K + scol;
  _Float16* lA = &As[(wave * 16) * 64];
  _Float16* lB = &Bs[(wave * 32) * 64];
  for (int k0 = 0; k0 < K; k0 += 64) {
    __syncthreads();
#pragma unroll
    for (int i = 0; i < 2; i++)
      async16(lA + i * 8 * 64, ga + (size_t)(8 * i) * K + k0);
#pragma unroll
    for (int i = 0; i < 4; i++)
      async16(lB + i * 8 * 64, gb + (size_t)(8 * i) * K + k0);
    __syncthreads();
#pragma unroll
    for (int k2 = 0; k2 < 2; k2++) {
      const int sb = k2 * 4 + (lane >> 4);
      const int so = (sb ^ xr) * 8;
      half8 af[2], bf[4];
#pragma unroll
      for (int i = 0; i < 2; i++)
        af[i] = *(const half8*)&As[(wr + i * 16 + fr) * 64 + so];
#pragma unroll
      for (int j = 0; j < 4; j++)
        bf[j] = *(const half8*)&Bs[(wc + j * 16 + fr) * 64 + so];
#pragma unroll
      for (int i = 0; i < 2; i++)
#pragma unroll
        for (int j = 0; j < 4; j++)
          acc[i][j] = __builtin_amdgcn_mfma_f32_16x16x32_f16(af[i], bf[j], acc[i][j], 0, 0, 0);
    }
  }
  const int rg = (lane >> 4) * 4;
#pragma unroll
  for (int i = 0; i < 2; i++) {
#pragma unroll
    for (int j = 0; j < 4; j++) {
      int col = bn + wc + j * 16 + fr;
#pragma unroll
      for (int r = 0; r < 4; r++) {
        int row = bm + wr + i * 16 + rg + r;
        float v = acc[i][j][r] * alpha;
        if (OUT_F32)
          ((float*)C)[z * strideC + (size_t)row * N + col] = v;
        else
          ((_Float16*)C)[z * strideC + (size_t)row * N + col] = (_Float16)v;
      }
    }
  }
}

// ---------------- block reduce helper (256 threads, 4 waves) ----------------
__device__ __forceinline__ float block_reduce(float v, bool do_max, float* wbuf, int tid) {
#pragma unroll
  for (int m = 32; m; m >>= 1) {
    float o = __shfl_xor(v, m);
    v = do_max ? fmaxf(v, o) : (v + o);
  }
  if ((tid & 63) == 0) wbuf[tid >> 6] = v;
  __syncthreads();
  float r = do_max ? fmaxf(fmaxf(wbuf[0], wbuf[1]), fmaxf(wbuf[2], wbuf[3]))
                   : (wbuf[0] + wbuf[1] + wbuf[2] + wbuf[3]);
  __syncthreads();
  return r;
}

// ---------------- pass 1: per-compact-row softmax stats (compact cols) -----
__global__ __launch_bounds__(256) void row_stats_kernel(
    const _Float16* __restrict__ S, const float* __restrict__ row_w,
    const int* __restrict__ keepM, const int* __restrict__ cntN,
    float4* __restrict__ stats_c) {
  const int r = blockIdx.x;
  if (r >= *keepM) return;
  __shared__ float wbuf[4];
  const int b = blockIdx.z;
  const int tid = threadIdx.x;
  const int cnt = cntN[b];
  if (cnt == 0) return;  // batch-wide uniform corner handled in combine
  const float w = row_w[r];
  const _Float16* sp = S + ((size_t)b * 2048 + r) * 4096 + tid * 16;
  float a[16];
  {
    half8 v0 = *(const half8*)(sp);
    half8 v1 = *(const half8*)(sp + 8);
    const int c0 = tid * 16;
#pragma unroll
    for (int u = 0; u < 8; u++) {
      a[u] = (c0 + u < cnt) ? (float)v0[u] : MASK_FILL;
      a[8 + u] = (c0 + 8 + u < cnt) ? (float)v1[u] : MASK_FILL;
    }
  }
  float mx = a[0];
#pragma unroll
  for (int c = 1; c < 16; c++) mx = fmaxf(mx, a[c]);
  mx = block_reduce(mx, true, wbuf, tid);
  float ls = 0.f;
#pragma unroll
  for (int c = 0; c < 16; c++) ls += expf(a[c] - mx);
  float denom = block_reduce(ls, false, wbuf, tid);
  if (tid == 0)
    stats_c[(size_t)b * 2048 + r] = make_float4(mx, w / denom, 0.f, 0.f);
}

// ---------------- pass 2: ds-weighted combine (compact layout) -------------
__global__ __launch_bounds__(256) void combine_kernel(
    const _Float16* __restrict__ S, const float4* __restrict__ stats_c,
    const int* __restrict__ start, const int* __restrict__ cntN,
    float* __restrict__ ca) {
  const int kd = blockIdx.x;
  const int b = blockIdx.z;
  const int i = blockIdx.y * 512 + threadIdx.x * 2;
  const int i0 = start[kd], i1 = start[kd + 1];
  const int cnt = cntN[b];
  float acc0, acc1;
  if (i0 == i1 || cnt == 0) {
    acc0 = acc1 = 1.0f / 4096.0f;
  } else if (i >= cnt) {
    acc0 = acc1 = 0.f;
  } else {
    acc0 = 0.f;
    acc1 = 0.f;
    const _Float16* sp = S + ((size_t)b * 2048 + i0) * 4096 + i;
    for (int r = i0; r < i1; r++, sp += 4096) {
      float4 s4 = stats_c[(size_t)b * 2048 + r];
      half2v v = *(const half2v*)sp;
      acc0 += s4.y * expf((float)v[0] - s4.x);
      acc1 += s4.y * expf((float)v[1] - s4.x);
    }
    if (i + 1 >= cnt) acc1 = 0.f;  // odd-cnt edge
  }
  float2 rr = {acc0, acc1};
  *(float2*)&ca[((size_t)b * 64 + kd) * 4096 + i] = rr;
}

// ---------------- t partial: t[b*64+m][j] = sum_i ca_c[b][m][i]*xh_c[b][i][j]
__global__ __launch_bounds__(256) void t_partial_kernel(
    const float* __restrict__ ca,     // [4][64][4096] compact
    const _Float16* __restrict__ xh,  // [4][4096][768] f16 compact (permuted)
    float* __restrict__ t_part) {     // [16][256][768]
  __shared__ float cas[64][68];
  __shared__ float xs[64][132];
  const int jt = blockIdx.x;  // 0..5
  const int nc = blockIdx.y;  // 0..15
  const int b = blockIdx.z;   // 0..3
  const int tid = threadIdx.x;
  const int tm = tid >> 4, tj = tid & 15;
  const int r = tid >> 2;
  const int cg = (tid & 3) * 16;
  const int cc = (tid & 3) * 32;
  float acc[4][8] = {};
  for (int n0 = nc * 256; n0 < nc * 256 + 256; n0 += 64) {
    __syncthreads();
    const float* cap = ca + (size_t)(b * 64 + r) * 4096 + n0 + cg;
#pragma unroll
    for (int u = 0; u < 16; u += 4)
      *(float4*)&cas[r][cg + u] = *(const float4*)(cap + u);
    const _Float16* xp = xh + ((size_t)b * 4096 + n0 + r) * 768 + jt * 128 + cc;
#pragma unroll
    for (int u = 0; u < 32; u += 8) {
      half8 hv = *(const half8*)(xp + u);
#pragma unroll
      for (int q = 0; q < 8; q++) xs[r][cc + u + q] = (float)hv[q];
    }
    __syncthreads();
#pragma unroll 8
    for (int nn = 0; nn < 64; ++nn) {
      float cm[4], xj[8];
#pragma unroll
      for (int i = 0; i < 4; i++) cm[i] = cas[tm * 4 + i][nn];
#pragma unroll
      for (int j = 0; j < 8; j++) xj[j] = xs[nn][tj * 8 + j];
#pragma unroll
      for (int i = 0; i < 4; i++)
#pragma unroll
        for (int j = 0; j < 8; j++) acc[i][j] += cm[i] * xj[j];
    }
  }
#pragma unroll
  for (int i = 0; i < 4; i++)
#pragma unroll
    for (int j = 0; j < 8; j++)
      t_part[((size_t)nc * 256 + b * 64 + tm * 4 + i) * 768 + jt * 128 + tj * 8 + j] = acc[i][j];
}

// reduce partials and cast to f16 for the pooled GEMM
__global__ __launch_bounds__(256) void t_reduce_kernel(
    const float* __restrict__ t_part, _Float16* __restrict__ th) {
  int i = blockIdx.x * 256 + threadIdx.x;  // < 196608
  float s = 0.f;
#pragma unroll
  for (int nc = 0; nc < 16; ++nc) s += t_part[(size_t)nc * 196608 + i];
  th[i] = (_Float16)s;
}

// ---------------- LayerNorm + final projection ----------------
__global__ __launch_bounds__(256) void ln_out_kernel(
    const float* __restrict__ pooled, const float* __restrict__ Wo,
    const float* __restrict__ bo, const float* __restrict__ gamma,
    const float* __restrict__ beta, float* __restrict__ out) {
  __shared__ float wbuf[4];
  const int row = blockIdx.x, tid = threadIdx.x;
  float p[3];
#pragma unroll
  for (int u = 0; u < 3; u++) p[u] = pooled[(size_t)row * 768 + tid + u * 256];
  float s1 = p[0] + p[1] + p[2];
  float s2 = p[0] * p[0] + p[1] * p[1] + p[2] * p[2];
  s1 = block_reduce(s1, false, wbuf, tid);
  s2 = block_reduce(s2, false, wbuf, tid);
  float mean = s1 * (1.f / 768.f);
  float var = s2 * (1.f / 768.f) - mean * mean;
  float rstd = rsqrtf(var + LN_EPS);
  float accv = 0.f;
#pragma unroll
  for (int u = 0; u < 3; u++) {
    int i = tid + u * 256;
    float y = (p[u] - mean) * rstd * gamma[i] + beta[i];
    accv += y * Wo[i];
  }
  accv = block_reduce(accv, false, wbuf, tid);
  if (tid == 0) out[row] = accv + bo[0];
}

extern "C" void kernel_launch(void* const* d_in, const int* in_sizes, int n_in,
                              void* d_out, int out_size, void* d_ws, size_t ws_size,
                              hipStream_t stream) {
  const float* x = (const float*)d_in[0];
  const float* enc = (const float*)d_in[1];
  const int* dmask = (const int*)d_in[2];
  const int* amask = (const int*)d_in[3];
  const float* Wk = (const float*)d_in[4];
  const float* Wv = (const float*)d_in[5];
  const float* Wo = (const float*)d_in[6];
  const float* bo = (const float*)d_in[7];
  const float* gamma = (const float*)d_in[8];
  const float* beta = (const float*)d_in[9];
  float* out = (float*)d_out;

  char* ws = (char*)d_ws;
  size_t off = 0;
  auto alloc = [&](size_t bytes) -> char* {
    char* p = ws + off;
    off += (bytes + 255) & ~((size_t)255);
    return p;
  };
  _Float16* xh_c = (_Float16*)alloc((size_t)16384 * 768 * 2);
  _Float16* wkT = (_Float16*)alloc((size_t)768 * 768 * 2);
  _Float16* wvh = (_Float16*)alloc((size_t)768 * 768 * 2);
  _Float16* enc_c = (_Float16*)alloc((size_t)2048 * 768 * 2);
  _Float16* encK_c = (_Float16*)alloc((size_t)2048 * 768 * 2);
  float* ca = (float*)alloc((size_t)4 * 64 * 4096 * 4);
  float* t_part = (float*)alloc((size_t)16 * 256 * 768 * 4);
  _Float16* th = (_Float16*)alloc((size_t)256 * 768 * 2);
  float* pooled = (float*)alloc((size_t)256 * 768 * 4);
  float4* stats_c = (float4*)alloc((size_t)4 * 2048 * 16);
  int* rowmap = (int*)alloc(2048 * 4);
  float* row_w = (float*)alloc(2048 * 4);
  int* start = (int*)alloc(65 * 4);
  int* keepM = (int*)alloc(4);
  int* perm = (int*)alloc((size_t)4 * 4096 * 4);
  int* cntN = (int*)alloc(4 * 4);

  // batched path needs 4 S buffers (67.1 MB); fallback needs 1 (16.8 MB)
  const size_t s_one = (size_t)2048 * 4096 * 2;
  const bool batched = (off + 4 * s_one) <= ws_size;
  _Float16* S = (_Float16*)alloc(batched ? 4 * s_one : s_one);

  const float scale = 0.036084391824351615f;  // 1/sqrt(768)

  prep_all_kernel<<<5, 256, 0, stream>>>(
      dmask, amask, rowmap, row_w, start, keepM, perm, cntN);
  gather_cast_all_kernel<<<19584, 256, 0, stream>>>(
      x, enc, Wv, Wk, perm, rowmap, keepM, xh_c, enc_c, wvh, wkT);

  // encK_c = enc_c @ Wk   [keepM x 768]
  gemm_f16_kernel<false, false><<<dim3(32, 6), 256, 0, stream>>>(
      enc_c, wkT, encK_c, 2048, 768, 768, 1.0f, 0, 0, keepM, nullptr);

  if (batched) {
    gemm_f16_kernel<false, true><<<dim3(32, 32, 4), 256, 0, stream>>>(
        encK_c, xh_c, S, 2048, 4096, 768, scale,
        (size_t)4096 * 768, (size_t)2048 * 4096, keepM, cntN);
    row_stats_kernel<<<dim3(2048, 1, 4), 256, 0, stream>>>(
        S, row_w, keepM, cntN, stats_c);
    combine_kernel<<<dim3(64, 8, 4), 256, 0, stream>>>(
        S, stats_c, start, cntN, ca);
  } else {
    for (int b = 0; b < 4; b++) {
      gemm_f16_kernel<false, true><<<dim3(32, 32), 256, 0, stream>>>(
          encK_c, xh_c + (size_t)b * 4096 * 768, S, 2048, 4096, 768, scale,
          0, 0, keepM, cntN + b);
      row_stats_kernel<<<dim3(2048, 1, 1), 256, 0, stream>>>(
          S, row_w, keepM, cntN + b, stats_c + (size_t)b * 2048);
      combine_kernel<<<dim3(64, 8, 1), 256, 0, stream>>>(
          S, stats_c + (size_t)b * 2048, start, cntN + b,
          ca + (size_t)b * 64 * 4096);
    }
  }

  // t = ca_c @ xh_c  (fp32 accum), split over n-chunks then reduced to f16
  t_partial_kernel<<<dim3(6, 16, 4), 256, 0, stream>>>(ca, xh_c, t_part);
  t_reduce_kernel<<<768, 256, 0, stream>>>(t_part, th);
  // pooled = t @ Wv^T  [256 x 768] fp32
  gemm_f16_kernel<true, false><<<dim3(4, 6), 256, 0, stream>>>(
      th, wvh, pooled, 256, 768, 768, 1.0f, 0, 0, nullptr, nullptr);
  ln_out_kernel<<<256, 256, 0, stream>>>(pooled, Wo, bo, gamma, beta, out);
}